// Round 4
// baseline (429.652 us; speedup 1.0000x reference)
//
#include <hip/hip_runtime.h>
#include <math.h>

// CRF layer: B=2048 sequences, T=512 max steps, C=32 tags.
// out = [ tags as float (B*T) | loss (1) ], total 1048577 floats.
#define BB 2048
#define TT 512
#define CC 32

#if __has_builtin(__builtin_amdgcn_exp2f)
#define EXP2F __builtin_amdgcn_exp2f
#else
#define EXP2F exp2f
#endif
#if __has_builtin(__builtin_amdgcn_logf)
#define LOG2F __builtin_amdgcn_logf   // v_log_f32 computes log2
#else
#define LOG2F log2f
#endif

#define LOG2E 1.4426950408889634f
#define LN2   0.6931471805599453f

__global__ void zero_loss_kernel(float* __restrict__ out) {
  if (threadIdx.x == 0) out[(size_t)BB * TT] = 0.0f;
}

// Setup: counting-sort sequence indices by length (descending) into perm,
// and zero the loss accumulator. One block, TT=512 threads.
__global__ void schedule_kernel(const int* __restrict__ seqlen,
                                int* __restrict__ perm,
                                float* __restrict__ out) {
  __shared__ int s[TT];
  __shared__ int off[TT];
  const int tid = threadIdx.x;
  if (tid == 0) out[(size_t)BB * TT] = 0.0f;
  s[tid] = 0;
  __syncthreads();
  for (int b = tid; b < BB; b += TT) atomicAdd(&s[seqlen[b] - 1], 1);
  __syncthreads();
  for (int d = 1; d < TT; d <<= 1) {       // inclusive suffix scan
    int v = s[tid] + ((tid + d < TT) ? s[tid + d] : 0);
    __syncthreads();
    s[tid] = v;
    __syncthreads();
  }
  off[tid] = (tid + 1 < TT) ? s[tid + 1] : 0;  // exclusive suffix sum
  __syncthreads();
  for (int b = tid; b < BB; b += TT) {
    int pos = atomicAdd(&off[seqlen[b] - 1], 1);
    perm[pos] = b;  // descending length order (ties arbitrary)
  }
}

// DPP row rotate-right by K: lane i reads lane (i-K)&15 within its 16-row.
#define ROR(dst, src, K)                                                     \
  dst = __int_as_float(__builtin_amdgcn_update_dpp(                          \
      0, __float_as_int(src), 0x120 | (K), 0xF, 0xF, false));

// ---- cross-lane xor16 / xor32 without DS latency (gfx950 permlane swaps) --
// v_permlane32_swap_b32(a,b): res0 = [a.lo, b.lo], res1 = [a.hi, b.hi].
// With a==b==x: res0 = [x.lo, x.lo], res1 = [x.hi, x.hi]
//   -> x[lane^32] = (lane&32) ? res0 : res1.
// v_permlane16_swap_b32(a,b): swaps odd 16-rows of a with even rows of b.
// With a==b==x: res0 = [x.r0,x.r0,x.r2,x.r2], res1 = [x.r1,x.r1,x.r3,x.r3]
//   -> x[lane^16] = (lane&16) ? res0 : res1.
__device__ __forceinline__ float xor16f(float x, int lane) {
#if __has_builtin(__builtin_amdgcn_permlane16_swap)
  auto r = __builtin_amdgcn_permlane16_swap(__float_as_uint(x),
                                            __float_as_uint(x), false, false);
  return __uint_as_float((lane & 16) ? r[0] : r[1]);
#else
  // BitMode swizzle xor-16: (16<<10)|31 = 0x401F (proven encoding)
  return __int_as_float(
      __builtin_amdgcn_ds_swizzle(__float_as_int(x), 0x401F));
#endif
}
__device__ __forceinline__ float xor32f(float x, int lane) {
#if __has_builtin(__builtin_amdgcn_permlane32_swap)
  auto r = __builtin_amdgcn_permlane32_swap(__float_as_uint(x),
                                            __float_as_uint(x), false, false);
  return __uint_as_float((lane & 32) ? r[0] : r[1]);
#else
  return __shfl_xor(x, 32);
#endif
}
__device__ __forceinline__ int xor32i(int x, int lane) {
#if __has_builtin(__builtin_amdgcn_permlane32_swap)
  auto r = __builtin_amdgcn_permlane32_swap((unsigned)x, (unsigned)x,
                                            false, false);
  return (int)((lane & 32) ? r[0] : r[1]);
#else
  return __shfl_xor(x, 32);
#endif
}

// Two waves per block. If perm != nullptr, block k processes sequences
// perm[k] then perm[BB-1-k] (length-balanced pair); else block k processes
// just sequence k (fallback when no workspace is available).
//   wave 0 (V): Viterbi, alphas IN REGISTERS (DPP rotations; lower lanes
//       reduce own 16-row, upper lanes the mirrored row; exact min-index
//       tie-break). Only DS op per step: 1 backpointer byte write.
//   wave 1 (F): forward pass in scaled linear domain, register alphas,
//       permlane exchanges, DPP rotate-fold renorm. Zero DS ops per step.
// Waves never sync.
__global__ __launch_bounds__(128, 4) void crf_kernel(
    const float* __restrict__ logits,     // [B, T, C]
    const int*   __restrict__ seqlen,     // [B]
    const int*   __restrict__ labels,     // [B, T]
    const float* __restrict__ trans,      // [C, C]  trans[p*C + c]
    float*       __restrict__ out,        // [B*T + 1]
    const int*   __restrict__ perm)       // [B] desc-length order, or nullptr
{
  __shared__ __align__(16) unsigned char bp_s[(TT - 1) * CC]; // 16,352 B
  __shared__ unsigned char tag_s[TT];

  const int lane = threadIdx.x & 63;
  const int wv   = threadIdx.x >> 6;     // 0 = viterbi, 1 = forward
  const int k    = blockIdx.x;

  const int bs0 = perm ? perm[k] : k;
  const int bs1 = perm ? perm[BB - 1 - k] : -1;

  const int i  = lane & 15;
  const int c  = lane & 31;              // column; lanes 32-63 mirror 0-31
  const int r  = (lane >> 4) & 1;        // row of own column
  const int pr = (lane < 32) ? r : 1 - r;  // prev-row group this lane reduces

  if (wv == 0) {
    // ================= Viterbi wave (register alphas, DPP) =================
    // tr2[k] pairs with rot(base,k): prev tag p_k = pr*16 + ((i-k)&15)
    float tr2[16];
    int   pidx[16];
#pragma unroll
    for (int kk = 0; kk < 16; ++kk) {
      int p = pr * 16 + ((i - kk) & 15);
      pidx[kk] = p;
      tr2[kk] = trans[p * CC + c];
    }

    for (int sq = 0; sq < 2; ++sq) {
      const int b = sq ? bs1 : bs0;
      if (b < 0) break;
      const int len = seqlen[b];
      const float* lg = logits + (size_t)b * TT * CC;
      const size_t bT = (size_t)b * TT;

      float av = lg[c];                  // alpha, duplicated across halves

      // 3-deep logit prefetch, unclamped main loop + clamped tail
      const float* lgc = lg + c;
      float l0 = 0, l1 = 0, l2 = 0;
      {
        int r1 = 1 < len ? 1 : len - 1;
        int r2 = 2 < len ? 2 : len - 1;
        int r3 = 3 < len ? 3 : len - 1;
        l0 = lgc[r1 * CC]; l1 = lgc[r2 * CC]; l2 = lgc[r3 * CC];
      }

      auto vstep = [&](int t, float logit_c) {
        // base holds av over this lane's prev-row group, rotation-indexed
        float base = (lane < 32) ? av : xor16f(av, lane);
        float S[16];
        float x;
        S[0] = base + tr2[0];
        ROR(x, base, 1);  S[1]  = x + tr2[1];
        ROR(x, base, 2);  S[2]  = x + tr2[2];
        ROR(x, base, 3);  S[3]  = x + tr2[3];
        ROR(x, base, 4);  S[4]  = x + tr2[4];
        ROR(x, base, 5);  S[5]  = x + tr2[5];
        ROR(x, base, 6);  S[6]  = x + tr2[6];
        ROR(x, base, 7);  S[7]  = x + tr2[7];
        ROR(x, base, 8);  S[8]  = x + tr2[8];
        ROR(x, base, 9);  S[9]  = x + tr2[9];
        ROR(x, base, 10); S[10] = x + tr2[10];
        ROR(x, base, 11); S[11] = x + tr2[11];
        ROR(x, base, 12); S[12] = x + tr2[12];
        ROR(x, base, 13); S[13] = x + tr2[13];
        ROR(x, base, 14); S[14] = x + tr2[14];
        ROR(x, base, 15); S[15] = x + tr2[15];

        // tree max (depth 4) over this 16-row group
        float m8[8];
#pragma unroll
        for (int kk = 0; kk < 8; ++kk) m8[kk] = fmaxf(S[kk], S[kk + 8]);
#pragma unroll
        for (int kk = 0; kk < 4; ++kk) m8[kk] = fmaxf(m8[kk], m8[kk + 4]);
        float best = fmaxf(fmaxf(m8[0], m8[2]), fmaxf(m8[1], m8[3]));

        // first-index = min prev-tag where equal (order-independent, exact)
        int t8[16];
#pragma unroll
        for (int kk = 0; kk < 16; ++kk)
          t8[kk] = (S[kk] == best) ? pidx[kk] : 63;
#pragma unroll
        for (int kk = 0; kk < 8; ++kk) t8[kk] = min(t8[kk], t8[kk + 8]);
#pragma unroll
        for (int kk = 0; kk < 4; ++kk) t8[kk] = min(t8[kk], t8[kk + 4]);
        int bi = min(min(t8[0], t8[2]), min(t8[1], t8[3]));

        // cross-half combine (lower prev-tag wins ties) — permlane, no DS
        float ov = xor32f(best, lane);
        int   oi = xor32i(bi, lane);
        bool take = (ov > best) || (ov == best && oi < bi);
        best = take ? ov : best;
        int bpi = take ? oi : bi;
        av = logit_c + best;

        if (lane < 32) bp_s[(t - 1) * CC + c] = (unsigned char)bpi;
      };

      int t = 1;
      int tmain = len - 3;                 // t+3 <= len-1 guaranteed
      for (; t < tmain; ++t) {
        float lc = l0; l0 = l1; l1 = l2;
        l2 = lgc[(t + 3) * CC];
        vstep(t, lc);
      }
      for (; t < len; ++t) {
        float lc = l0; l0 = l1; l1 = l2;
        int rn = t + 3; rn = rn < len ? rn : len - 1;
        l2 = lgc[rn * CC];
        vstep(t, lc);
      }

      // last tag: argmax over c (first index on ties) — proven butterfly
      float v = av; int idx = c;
#pragma unroll
      for (int d = 1; d < 32; d <<= 1) {
        float v2 = __shfl_xor(v, d, 32);
        int   i2 = __shfl_xor(idx, d, 32);
        if (v2 > v || (v2 == v && i2 < idx)) { v = v2; idx = i2; }
      }

      // backtrace: register-prefetched rows, in-register byte select
      if (lane == 0) {
        int tag = idx;
        tag_s[len - 1] = (unsigned char)tag;
        const uint4* bp4 = (const uint4*)bp_s;   // row r = bp4[2r], bp4[2r+1]
        uint4 Ra[3], Rb[3];
#pragma unroll
        for (int kk = 0; kk < 3; ++kk) {
          int rr = len - 2 - kk;
          if (rr >= 0) { Ra[kk] = bp4[2 * rr]; Rb[kk] = bp4[2 * rr + 1]; }
        }
        for (int tt = len - 1; tt > 0; --tt) {
          uint4 ua = Ra[0], ub = Rb[0];
          Ra[0] = Ra[1]; Rb[0] = Rb[1];
          Ra[1] = Ra[2]; Rb[1] = Rb[2];
          int rr = tt - 4;
          if (rr >= 0) { Ra[2] = bp4[2 * rr]; Rb[2] = bp4[2 * rr + 1]; }
          uint4 u4;
          u4.x = (tag & 16) ? ub.x : ua.x;
          u4.y = (tag & 16) ? ub.y : ua.y;
          u4.z = (tag & 16) ? ub.z : ua.z;
          u4.w = (tag & 16) ? ub.w : ua.w;
          unsigned lo = (tag & 8) ? u4.z : u4.x;
          unsigned hi = (tag & 8) ? u4.w : u4.y;
          unsigned u1 = (tag & 4) ? hi : lo;
          tag = (int)((u1 >> ((tag & 3) * 8)) & 0xffu);
          tag_s[tt - 1] = (unsigned char)tag;
        }
      }

      // coalesced tag store (+ zero padding)
#pragma unroll
      for (int j = 0; j < 8; ++j) {
        int tt = lane + 64 * j;
        float val = (tt < len) ? (float)tag_s[tt] : 0.0f;
        out[bT + tt] = val;
      }
    }

  } else {
    // ================= Forward wave (scaled linear domain) =================
    // E[k] = exp(trans[p_k][c]) in DPP-rotation order
    float E[16];
#pragma unroll
    for (int kk = 0; kk < 16; ++kk) {
      int p = pr * 16 + ((i - kk) & 15);
      E[kk] = EXP2F(trans[p * CC + c] * LOG2E);
    }

    float loss_acc = 0.0f;

    for (int sq = 0; sq < 2; ++sq) {
      const int b = sq ? bs1 : bs0;
      if (b < 0) break;
      const int len = seqlen[b];
      const float* lg = logits + (size_t)b * TT * CC;
      const int* lab = labels + (size_t)b * TT;

      float P   = EXP2F(lg[c] * LOG2E);  // scaled linear alpha for column c
      float Acc = 0.0f;                  // accumulated log2 scale (uniform)

      // 3-deep prefetch of exp(logit): exp computed at load time, off-chain
      const float* lgc = lg + c;
      float e0 = 0, e1 = 0, e2 = 0;
      {
        int r1 = 1 < len ? 1 : len - 1;
        int r2 = 2 < len ? 2 : len - 1;
        int r3 = 3 < len ? 3 : len - 1;
        e0 = EXP2F(lgc[r1 * CC] * LOG2E);
        e1 = EXP2F(lgc[r2 * CC] * LOG2E);
        e2 = EXP2F(lgc[r3 * CC] * LOG2E);
      }

      auto fstep = [&](float el) {
        float base = (lane < 32) ? P : xor16f(P, lane);
        float x;
        float a0 = base * E[0];
        ROR(x, base, 1);  float a1 = x * E[1];
        ROR(x, base, 2);  float a2 = x * E[2];
        ROR(x, base, 3);  float a3 = x * E[3];
        ROR(x, base, 4);  a0 = fmaf(x, E[4],  a0);
        ROR(x, base, 5);  a1 = fmaf(x, E[5],  a1);
        ROR(x, base, 6);  a2 = fmaf(x, E[6],  a2);
        ROR(x, base, 7);  a3 = fmaf(x, E[7],  a3);
        ROR(x, base, 8);  a0 = fmaf(x, E[8],  a0);
        ROR(x, base, 9);  a1 = fmaf(x, E[9],  a1);
        ROR(x, base, 10); a2 = fmaf(x, E[10], a2);
        ROR(x, base, 11); a3 = fmaf(x, E[11], a3);
        ROR(x, base, 12); a0 = fmaf(x, E[12], a0);
        ROR(x, base, 13); a1 = fmaf(x, E[13], a1);
        ROR(x, base, 14); a2 = fmaf(x, E[14], a2);
        ROR(x, base, 15); a3 = fmaf(x, E[15], a3);
        float part = (a0 + a1) + (a2 + a3);      // this lane's 16-row partial
        float oth  = xor32f(part, lane);         // other row's partial
        P = el * (part + oth);
      };

      auto renorm = [&]() {
        // max over 32 columns via DPP rotate-fold (order-independent, exact)
        float m = P, y;
        ROR(y, m, 8); m = fmaxf(m, y);
        ROR(y, m, 4); m = fmaxf(m, y);
        ROR(y, m, 2); m = fmaxf(m, y);
        ROR(y, m, 1); m = fmaxf(m, y);
        m = fmaxf(m, xor16f(m, lane));
        int e = (int)(__float_as_uint(m) >> 23) - 127;  // floor(log2 m)
        P = ldexpf(P, -e);                              // exact scaling
        Acc += (float)e;
      };

      int t = 1;
      int tmain = len - 3;
      for (; t < tmain; ++t) {
        float ec = e0; e0 = e1; e1 = e2;
        e2 = EXP2F(lgc[(t + 3) * CC] * LOG2E);
        fstep(ec);
        if ((t & 3) == 0) renorm();
      }
      for (; t < len; ++t) {
        float ec = e0; e0 = e1; e1 = e2;
        int rn = t + 3; rn = rn < len ? rn : len - 1;
        e2 = EXP2F(lgc[rn * CC] * LOG2E);
        fstep(ec);
        if ((t & 3) == 0) renorm();
      }

      // gold-path score (unary + binary), lane-parallel over t
      float uacc = 0.0f, bacc = 0.0f;
#pragma unroll
      for (int j = 0; j < 8; ++j) {
        int tt = lane + 64 * j;
        if (tt < len) {
          int lt = lab[tt];
          uacc += lg[tt * CC + lt];
          if (tt + 1 < len) {
            int ln = lab[tt + 1];
            bacc += trans[lt * CC + ln];
          }
        }
      }
#pragma unroll
      for (int d = 32; d >= 1; d >>= 1) {
        uacc += __shfl_xor(uacc, d);
        bacc += __shfl_xor(bacc, d);
      }

      // log partition: rotate-fold sum of the 32 scaled alphas + scale
      float ss = P, y2;
      ROR(y2, ss, 8); ss += y2;
      ROR(y2, ss, 4); ss += y2;
      ROR(y2, ss, 2); ss += y2;
      ROR(y2, ss, 1); ss += y2;
      ss += xor16f(ss, lane);
      float log_norm = LN2 * (Acc + LOG2F(ss));

      loss_acc += (uacc + bacc - log_norm);
    }

    if (lane == 0) {
      atomicAdd(out + (size_t)BB * TT, loss_acc * (-1.0f / BB));
    }
  }
}

extern "C" void kernel_launch(void* const* d_in, const int* in_sizes, int n_in,
                              void* d_out, int out_size, void* d_ws, size_t ws_size,
                              hipStream_t stream) {
  const float* logits = (const float*)d_in[0];
  const int*   seqlen = (const int*)d_in[1];
  const int*   labels = (const int*)d_in[2];
  const float* trans  = (const float*)d_in[3];
  float* out = (float*)d_out;

  if (d_ws != nullptr && ws_size >= BB * sizeof(int)) {
    // Length-balanced pairing path: sort by length, pair long with short.
    int* perm = (int*)d_ws;
    schedule_kernel<<<1, TT, 0, stream>>>(seqlen, perm, out);
    crf_kernel<<<dim3(BB / 2), dim3(128), 0, stream>>>(
        logits, seqlen, labels, trans, out, perm);
  } else {
    // Fallback (no workspace): one sequence per block.
    zero_loss_kernel<<<1, 64, 0, stream>>>(out);
    crf_kernel<<<dim3(BB), dim3(128), 0, stream>>>(
        logits, seqlen, labels, trans, out, nullptr);
  }
}

// Round 5
// 409.678 us; speedup vs baseline: 1.0488x; 1.0488x over previous
//
#include <hip/hip_runtime.h>
#include <math.h>

// CRF layer: B=2048 sequences, T=512 max steps, C=32 tags.
// out = [ tags as float (B*T) | loss (1) ], total 1048577 floats.
#define BB 2048
#define TT 512
#define CC 32

#if __has_builtin(__builtin_amdgcn_exp2f)
#define EXP2F __builtin_amdgcn_exp2f
#else
#define EXP2F exp2f
#endif
#if __has_builtin(__builtin_amdgcn_logf)
#define LOG2F __builtin_amdgcn_logf   // v_log_f32 computes log2
#else
#define LOG2F log2f
#endif

#define LOG2E 1.4426950408889634f
#define LN2   0.6931471805599453f

__global__ void zero_loss_kernel(float* __restrict__ out) {
  if (threadIdx.x == 0) out[(size_t)BB * TT] = 0.0f;
}

// Setup: counting-sort sequence indices by length (descending) into perm,
// and zero the loss accumulator. One block, TT=512 threads.
__global__ void schedule_kernel(const int* __restrict__ seqlen,
                                int* __restrict__ perm,
                                float* __restrict__ out) {
  __shared__ int s[TT];
  __shared__ int off[TT];
  const int tid = threadIdx.x;
  if (tid == 0) out[(size_t)BB * TT] = 0.0f;
  s[tid] = 0;
  __syncthreads();
  for (int b = tid; b < BB; b += TT) atomicAdd(&s[seqlen[b] - 1], 1);
  __syncthreads();
  for (int d = 1; d < TT; d <<= 1) {       // inclusive suffix scan
    int v = s[tid] + ((tid + d < TT) ? s[tid + d] : 0);
    __syncthreads();
    s[tid] = v;
    __syncthreads();
  }
  off[tid] = (tid + 1 < TT) ? s[tid + 1] : 0;  // exclusive suffix sum
  __syncthreads();
  for (int b = tid; b < BB; b += TT) {
    int pos = atomicAdd(&off[seqlen[b] - 1], 1);
    perm[pos] = b;  // descending length order (ties arbitrary)
  }
}

// DPP row rotate-right by K: lane i reads lane (i-K)&15 within its 16-row.
#define ROR(dst, src, K)                                                     \
  dst = __int_as_float(__builtin_amdgcn_update_dpp(                          \
      0, __float_as_int(src), 0x120 | (K), 0xF, 0xF, false));

// ---- cross-lane xor16 / xor32 without DS latency (gfx950 permlane swaps) --
__device__ __forceinline__ float xor16f(float x, int lane) {
#if __has_builtin(__builtin_amdgcn_permlane16_swap)
  auto r = __builtin_amdgcn_permlane16_swap(__float_as_uint(x),
                                            __float_as_uint(x), false, false);
  return __uint_as_float((lane & 16) ? r[0] : r[1]);
#else
  return __int_as_float(
      __builtin_amdgcn_ds_swizzle(__float_as_int(x), 0x401F));
#endif
}
__device__ __forceinline__ float xor32f(float x, int lane) {
#if __has_builtin(__builtin_amdgcn_permlane32_swap)
  auto r = __builtin_amdgcn_permlane32_swap(__float_as_uint(x),
                                            __float_as_uint(x), false, false);
  return __uint_as_float((lane & 32) ? r[0] : r[1]);
#else
  return __shfl_xor(x, 32);
#endif
}
__device__ __forceinline__ int xor32i(int x, int lane) {
#if __has_builtin(__builtin_amdgcn_permlane32_swap)
  auto r = __builtin_amdgcn_permlane32_swap((unsigned)x, (unsigned)x,
                                            false, false);
  return (int)((lane & 32) ? r[0] : r[1]);
#else
  return __shfl_xor(x, 32);
#endif
}

// Two waves per block. If perm != nullptr, block k processes sequences
// perm[k] then perm[BB-1-k] (length-balanced pair); else block k processes
// just sequence k (fallback when no workspace is available).
//   wave 0 (V): Viterbi, alphas in registers (DPP rotations, permlane
//       exchanges, exact min-index tie-break). DS per step: 1 bp byte write.
//   wave 1 (F): forward pass in scaled linear domain, register alphas.
// Logit fetch: chunked 8-step double-bank register pipeline. The old rolled
// "3-deep rotation" forced s_waitcnt vmcnt(0) per step (copies need the
// data) -> every step paid full memory latency (~530 ns/step floor seen in
// R1-R4). Banks are statically indexed (full unroll) and alternate at the
// call sites, so loads for chunk k+1 stay in flight across chunk k's steps.
__global__ __launch_bounds__(128, 4) void crf_kernel(
    const float* __restrict__ logits,     // [B, T, C]
    const int*   __restrict__ seqlen,     // [B]
    const int*   __restrict__ labels,     // [B, T]
    const float* __restrict__ trans,      // [C, C]  trans[p*C + c]
    float*       __restrict__ out,        // [B*T + 1]
    const int*   __restrict__ perm)       // [B] desc-length order, or nullptr
{
  __shared__ __align__(16) unsigned char bp_s[(TT - 1) * CC]; // 16,352 B
  __shared__ unsigned char tag_s[TT];

  const int lane = threadIdx.x & 63;
  const int wv   = threadIdx.x >> 6;     // 0 = viterbi, 1 = forward
  const int k    = blockIdx.x;

  const int bs0 = perm ? perm[k] : k;
  const int bs1 = perm ? perm[BB - 1 - k] : -1;

  const int i  = lane & 15;
  const int c  = lane & 31;              // column; lanes 32-63 mirror 0-31
  const int r  = (lane >> 4) & 1;        // row of own column
  const int pr = (lane < 32) ? r : 1 - r;  // prev-row group this lane reduces

  if (wv == 0) {
    // ================= Viterbi wave (register alphas, DPP) =================
    float tr2[16];
    int   pidx[16];
#pragma unroll
    for (int kk = 0; kk < 16; ++kk) {
      int p = pr * 16 + ((i - kk) & 15);
      pidx[kk] = p;
      tr2[kk] = trans[p * CC + c];
    }

    for (int sq = 0; sq < 2; ++sq) {
      const int b = sq ? bs1 : bs0;
      if (b < 0) break;
      const int len = seqlen[b];
      const float* lg = logits + (size_t)b * TT * CC;
      const size_t bT = (size_t)b * TT;
      const float* lgc = lg + c;

      float av = lg[c];                  // alpha, duplicated across halves

      auto vstep = [&](int t, float logit_c) {
        float base = (lane < 32) ? av : xor16f(av, lane);
        float S[16];
        float x;
        S[0] = base + tr2[0];
        ROR(x, base, 1);  S[1]  = x + tr2[1];
        ROR(x, base, 2);  S[2]  = x + tr2[2];
        ROR(x, base, 3);  S[3]  = x + tr2[3];
        ROR(x, base, 4);  S[4]  = x + tr2[4];
        ROR(x, base, 5);  S[5]  = x + tr2[5];
        ROR(x, base, 6);  S[6]  = x + tr2[6];
        ROR(x, base, 7);  S[7]  = x + tr2[7];
        ROR(x, base, 8);  S[8]  = x + tr2[8];
        ROR(x, base, 9);  S[9]  = x + tr2[9];
        ROR(x, base, 10); S[10] = x + tr2[10];
        ROR(x, base, 11); S[11] = x + tr2[11];
        ROR(x, base, 12); S[12] = x + tr2[12];
        ROR(x, base, 13); S[13] = x + tr2[13];
        ROR(x, base, 14); S[14] = x + tr2[14];
        ROR(x, base, 15); S[15] = x + tr2[15];

        float m8[8];
#pragma unroll
        for (int kk = 0; kk < 8; ++kk) m8[kk] = fmaxf(S[kk], S[kk + 8]);
#pragma unroll
        for (int kk = 0; kk < 4; ++kk) m8[kk] = fmaxf(m8[kk], m8[kk + 4]);
        float best = fmaxf(fmaxf(m8[0], m8[2]), fmaxf(m8[1], m8[3]));

        int t8[16];
#pragma unroll
        for (int kk = 0; kk < 16; ++kk)
          t8[kk] = (S[kk] == best) ? pidx[kk] : 63;
#pragma unroll
        for (int kk = 0; kk < 8; ++kk) t8[kk] = min(t8[kk], t8[kk + 8]);
#pragma unroll
        for (int kk = 0; kk < 4; ++kk) t8[kk] = min(t8[kk], t8[kk + 4]);
        int bi = min(min(t8[0], t8[2]), min(t8[1], t8[3]));

        float ov = xor32f(best, lane);
        int   oi = xor32i(bi, lane);
        bool take = (ov > best) || (ov == best && oi < bi);
        best = take ? ov : best;
        int bpi = take ? oi : bi;
        av = logit_c + best;

        if (lane < 32) bp_s[(t - 1) * CC + c] = (unsigned char)bpi;
      };

      // chunked 8-step double-bank logit pipeline
      float Abk[8], Bbk[8];
      auto loadB = [&](float (&bk)[8], int t0) {
#pragma unroll
        for (int s = 0; s < 8; ++s) {
          int tt = t0 + s; tt = tt < len ? tt : len - 1;
          bk[s] = lgc[tt * CC];
        }
      };
      auto runB = [&](float (&bk)[8], int t0) {
#pragma unroll
        for (int s = 0; s < 8; ++s) {
          int tt = t0 + s;
          if (tt < len) vstep(tt, bk[s]);
        }
      };
      loadB(Abk, 1);
      for (int t0 = 1; t0 < len; t0 += 16) {
        loadB(Bbk, t0 + 8);
        runB(Abk, t0);
        if (t0 + 8 < len) {
          loadB(Abk, t0 + 16);
          runB(Bbk, t0 + 8);
        }
      }

      // last tag: argmax over c (first index on ties)
      float v = av; int idx = c;
#pragma unroll
      for (int d = 1; d < 32; d <<= 1) {
        float v2 = __shfl_xor(v, d, 32);
        int   i2 = __shfl_xor(idx, d, 32);
        if (v2 > v || (v2 == v && i2 < idx)) { v = v2; idx = i2; }
      }

      // backtrace: register-prefetched rows, in-register byte select
      if (lane == 0) {
        int tag = idx;
        tag_s[len - 1] = (unsigned char)tag;
        const uint4* bp4 = (const uint4*)bp_s;   // row r = bp4[2r], bp4[2r+1]
        uint4 Ra[3], Rb[3];
#pragma unroll
        for (int kk = 0; kk < 3; ++kk) {
          int rr = len - 2 - kk;
          if (rr >= 0) { Ra[kk] = bp4[2 * rr]; Rb[kk] = bp4[2 * rr + 1]; }
        }
#pragma unroll 4
        for (int tt = len - 1; tt > 0; --tt) {
          uint4 ua = Ra[0], ub = Rb[0];
          Ra[0] = Ra[1]; Rb[0] = Rb[1];
          Ra[1] = Ra[2]; Rb[1] = Rb[2];
          int rr = tt - 4;
          if (rr >= 0) { Ra[2] = bp4[2 * rr]; Rb[2] = bp4[2 * rr + 1]; }
          uint4 u4;
          u4.x = (tag & 16) ? ub.x : ua.x;
          u4.y = (tag & 16) ? ub.y : ua.y;
          u4.z = (tag & 16) ? ub.z : ua.z;
          u4.w = (tag & 16) ? ub.w : ua.w;
          unsigned lo = (tag & 8) ? u4.z : u4.x;
          unsigned hi = (tag & 8) ? u4.w : u4.y;
          unsigned u1 = (tag & 4) ? hi : lo;
          tag = (int)((u1 >> ((tag & 3) * 8)) & 0xffu);
          tag_s[tt - 1] = (unsigned char)tag;
        }
      }

      // coalesced tag store (+ zero padding)
#pragma unroll
      for (int j = 0; j < 8; ++j) {
        int tt = lane + 64 * j;
        float val = (tt < len) ? (float)tag_s[tt] : 0.0f;
        out[bT + tt] = val;
      }
    }

  } else {
    // ================= Forward wave (scaled linear domain) =================
    float E[16];
#pragma unroll
    for (int kk = 0; kk < 16; ++kk) {
      int p = pr * 16 + ((i - kk) & 15);
      E[kk] = EXP2F(trans[p * CC + c] * LOG2E);
    }

    float loss_acc = 0.0f;

    for (int sq = 0; sq < 2; ++sq) {
      const int b = sq ? bs1 : bs0;
      if (b < 0) break;
      const int len = seqlen[b];
      const float* lg = logits + (size_t)b * TT * CC;
      const int* lab = labels + (size_t)b * TT;
      const float* lgc = lg + c;

      float P   = EXP2F(lg[c] * LOG2E);  // scaled linear alpha for column c
      float Acc = 0.0f;                  // accumulated log2 scale (uniform)

      auto fstep = [&](float raw_logit) {
        // el off the serial P-chain: computed from bank value in parallel
        float el = EXP2F(raw_logit * LOG2E);
        float base = (lane < 32) ? P : xor16f(P, lane);
        float x;
        float a0 = base * E[0];
        ROR(x, base, 1);  float a1 = x * E[1];
        ROR(x, base, 2);  float a2 = x * E[2];
        ROR(x, base, 3);  float a3 = x * E[3];
        ROR(x, base, 4);  a0 = fmaf(x, E[4],  a0);
        ROR(x, base, 5);  a1 = fmaf(x, E[5],  a1);
        ROR(x, base, 6);  a2 = fmaf(x, E[6],  a2);
        ROR(x, base, 7);  a3 = fmaf(x, E[7],  a3);
        ROR(x, base, 8);  a0 = fmaf(x, E[8],  a0);
        ROR(x, base, 9);  a1 = fmaf(x, E[9],  a1);
        ROR(x, base, 10); a2 = fmaf(x, E[10], a2);
        ROR(x, base, 11); a3 = fmaf(x, E[11], a3);
        ROR(x, base, 12); a0 = fmaf(x, E[12], a0);
        ROR(x, base, 13); a1 = fmaf(x, E[13], a1);
        ROR(x, base, 14); a2 = fmaf(x, E[14], a2);
        ROR(x, base, 15); a3 = fmaf(x, E[15], a3);
        float part = (a0 + a1) + (a2 + a3);      // this lane's 16-row partial
        float oth  = xor32f(part, lane);         // other row's partial
        P = el * (part + oth);
      };

      auto renorm = [&]() {
        float m = P, y;
        ROR(y, m, 8); m = fmaxf(m, y);
        ROR(y, m, 4); m = fmaxf(m, y);
        ROR(y, m, 2); m = fmaxf(m, y);
        ROR(y, m, 1); m = fmaxf(m, y);
        m = fmaxf(m, xor16f(m, lane));
        int e = (int)(__float_as_uint(m) >> 23) - 127;  // floor(log2 m)
        P = ldexpf(P, -e);                              // exact scaling
        Acc += (float)e;
      };

      // chunked 8-step double-bank logit pipeline (raw values in banks)
      float Abk[8], Bbk[8];
      auto loadB = [&](float (&bk)[8], int t0) {
#pragma unroll
        for (int s = 0; s < 8; ++s) {
          int tt = t0 + s; tt = tt < len ? tt : len - 1;
          bk[s] = lgc[tt * CC];
        }
      };
      auto runB = [&](float (&bk)[8], int t0) {
#pragma unroll
        for (int s = 0; s < 8; ++s) {
          int tt = t0 + s;
          if (tt < len) {
            fstep(bk[s]);
            if ((tt & 3) == 0) renorm();
          }
        }
      };
      loadB(Abk, 1);
      for (int t0 = 1; t0 < len; t0 += 16) {
        loadB(Bbk, t0 + 8);
        runB(Abk, t0);
        if (t0 + 8 < len) {
          loadB(Abk, t0 + 16);
          runB(Bbk, t0 + 8);
        }
      }

      // gold-path score (unary + binary), lane-parallel over t
      float uacc = 0.0f, bacc = 0.0f;
#pragma unroll
      for (int j = 0; j < 8; ++j) {
        int tt = lane + 64 * j;
        if (tt < len) {
          int lt = lab[tt];
          uacc += lg[tt * CC + lt];
          if (tt + 1 < len) {
            int ln = lab[tt + 1];
            bacc += trans[lt * CC + ln];
          }
        }
      }
#pragma unroll
      for (int d = 32; d >= 1; d >>= 1) {
        uacc += __shfl_xor(uacc, d);
        bacc += __shfl_xor(bacc, d);
      }

      // log partition: rotate-fold sum of the 32 scaled alphas + scale
      float ss = P, y2;
      ROR(y2, ss, 8); ss += y2;
      ROR(y2, ss, 4); ss += y2;
      ROR(y2, ss, 2); ss += y2;
      ROR(y2, ss, 1); ss += y2;
      ss += xor16f(ss, lane);
      float log_norm = LN2 * (Acc + LOG2F(ss));

      loss_acc += (uacc + bacc - log_norm);
    }

    if (lane == 0) {
      atomicAdd(out + (size_t)BB * TT, loss_acc * (-1.0f / BB));
    }
  }
}

extern "C" void kernel_launch(void* const* d_in, const int* in_sizes, int n_in,
                              void* d_out, int out_size, void* d_ws, size_t ws_size,
                              hipStream_t stream) {
  const float* logits = (const float*)d_in[0];
  const int*   seqlen = (const int*)d_in[1];
  const int*   labels = (const int*)d_in[2];
  const float* trans  = (const float*)d_in[3];
  float* out = (float*)d_out;

  if (d_ws != nullptr && ws_size >= BB * sizeof(int)) {
    // Length-balanced pairing path: sort by length, pair long with short.
    int* perm = (int*)d_ws;
    schedule_kernel<<<1, TT, 0, stream>>>(seqlen, perm, out);
    crf_kernel<<<dim3(BB / 2), dim3(128), 0, stream>>>(
        logits, seqlen, labels, trans, out, perm);
  } else {
    // Fallback (no workspace): one sequence per block.
    zero_loss_kernel<<<1, 64, 0, stream>>>(out);
    crf_kernel<<<dim3(BB), dim3(128), 0, stream>>>(
        logits, seqlen, labels, trans, out, nullptr);
  }
}

// Round 6
// 377.348 us; speedup vs baseline: 1.1386x; 1.0857x over previous
//
#include <hip/hip_runtime.h>
#include <math.h>

// CRF layer: B=2048 sequences, T=512 max steps, C=32 tags.
// out = [ tags as float (B*T) | loss (1) ], total 1048577 floats.
#define BB 2048
#define TT 512
#define CC 32

#if __has_builtin(__builtin_amdgcn_exp2f)
#define EXP2F __builtin_amdgcn_exp2f
#else
#define EXP2F exp2f
#endif
#if __has_builtin(__builtin_amdgcn_logf)
#define LOG2F __builtin_amdgcn_logf   // v_log_f32 computes log2
#else
#define LOG2F log2f
#endif

#define LOG2E 1.4426950408889634f
#define LN2   0.6931471805599453f

__global__ void zero_loss_kernel(float* __restrict__ out) {
  if (threadIdx.x == 0) out[(size_t)BB * TT] = 0.0f;
}

// Setup: counting-sort sequence indices by length (descending) into perm,
// and zero the loss accumulator. One block, TT=512 threads.
__global__ void schedule_kernel(const int* __restrict__ seqlen,
                                int* __restrict__ perm,
                                float* __restrict__ out) {
  __shared__ int s[TT];
  __shared__ int off[TT];
  const int tid = threadIdx.x;
  if (tid == 0) out[(size_t)BB * TT] = 0.0f;
  s[tid] = 0;
  __syncthreads();
  for (int b = tid; b < BB; b += TT) atomicAdd(&s[seqlen[b] - 1], 1);
  __syncthreads();
  for (int d = 1; d < TT; d <<= 1) {       // inclusive suffix scan
    int v = s[tid] + ((tid + d < TT) ? s[tid + d] : 0);
    __syncthreads();
    s[tid] = v;
    __syncthreads();
  }
  off[tid] = (tid + 1 < TT) ? s[tid + 1] : 0;  // exclusive suffix sum
  __syncthreads();
  for (int b = tid; b < BB; b += TT) {
    int pos = atomicAdd(&off[seqlen[b] - 1], 1);
    perm[pos] = b;  // descending length order (ties arbitrary)
  }
}

// DPP row rotate-right by K: lane i reads lane (i-K)&15 within its 16-row.
#define ROR(dst, src, K)                                                     \
  dst = __int_as_float(__builtin_amdgcn_update_dpp(                          \
      0, __float_as_int(src), 0x120 | (K), 0xF, 0xF, false));

// ---- cross-lane xor16 / xor32 without DS latency (gfx950 permlane swaps) --
__device__ __forceinline__ float xor16f(float x, int lane) {
#if __has_builtin(__builtin_amdgcn_permlane16_swap)
  auto r = __builtin_amdgcn_permlane16_swap(__float_as_uint(x),
                                            __float_as_uint(x), false, false);
  return __uint_as_float((lane & 16) ? r[0] : r[1]);
#else
  return __int_as_float(
      __builtin_amdgcn_ds_swizzle(__float_as_int(x), 0x401F));
#endif
}
__device__ __forceinline__ float xor32f(float x, int lane) {
#if __has_builtin(__builtin_amdgcn_permlane32_swap)
  auto r = __builtin_amdgcn_permlane32_swap(__float_as_uint(x),
                                            __float_as_uint(x), false, false);
  return __uint_as_float((lane & 32) ? r[0] : r[1]);
#else
  return __shfl_xor(x, 32);
#endif
}
__device__ __forceinline__ int xor32i(int x, int lane) {
#if __has_builtin(__builtin_amdgcn_permlane32_swap)
  auto r = __builtin_amdgcn_permlane32_swap((unsigned)x, (unsigned)x,
                                            false, false);
  return (int)((lane & 32) ? r[0] : r[1]);
#else
  return __shfl_xor(x, 32);
#endif
}

// Two waves per block; block k processes perm[k] then perm[BB-1-k]
// (length-balanced pair), or just seq k if no workspace.
//   wave 0 (V): Viterbi forward, alphas in registers (DPP + permlane).
//       NEW: every 4th step composes the last 4 backpointer maps via 3
//       ds_bpermute (off the alpha chain, exact integer map composition)
//       and stores one packed dword [t-1|t-2|t-3|t-4] per tag.  Backtrace
//       then needs ONE dependent LDS dword load per 4 steps (~130 total
//       instead of ~513 full-latency iterations — the serial loop that was
//       invariant across R1-R5 and is the suspected hidden half of the
//       V-wave's critical path).
//   wave 1 (F): forward pass in scaled linear domain (unchanged from R5).
// launch_bounds min-waves 4->2: VGPR=56 at cap 128 was strangling ILP of
// the 16-wide ROR/bank working set; residency is grid-limited (2 waves/SIMD)
// so a 256-VGPR cap is free.
__global__ __launch_bounds__(128, 2) void crf_kernel(
    const float* __restrict__ logits,     // [B, T, C]
    const int*   __restrict__ seqlen,     // [B]
    const int*   __restrict__ labels,     // [B, T]
    const float* __restrict__ trans,      // [C, C]  trans[p*C + c]
    float*       __restrict__ out,        // [B*T + 1]
    const int*   __restrict__ perm)       // [B] desc-length order, or nullptr
{
  __shared__ __align__(16) unsigned char bp_s[(TT - 1) * CC]; // 16,352 B
  __shared__ __align__(16) unsigned gp_s[(TT / 4) * CC];      // 16,384 B
  __shared__ unsigned char tag_s[TT];

  const int lane = threadIdx.x & 63;
  const int wv   = threadIdx.x >> 6;     // 0 = viterbi, 1 = forward
  const int k    = blockIdx.x;

  const int bs0 = perm ? perm[k] : k;
  const int bs1 = perm ? perm[BB - 1 - k] : -1;

  const int i  = lane & 15;
  const int c  = lane & 31;              // column; lanes 32-63 mirror 0-31
  const int r  = (lane >> 4) & 1;        // row of own column
  const int pr = (lane < 32) ? r : 1 - r;  // prev-row group this lane reduces

  if (wv == 0) {
    // ================= Viterbi wave (register alphas, DPP) =================
    float tr2[16];
    int   pidx[16];
#pragma unroll
    for (int kk = 0; kk < 16; ++kk) {
      int p = pr * 16 + ((i - kk) & 15);
      pidx[kk] = p;
      tr2[kk] = trans[p * CC + c];
    }

    for (int sq = 0; sq < 2; ++sq) {
      const int b = sq ? bs1 : bs0;
      if (b < 0) break;
      const int len = seqlen[b];
      const float* lg = logits + (size_t)b * TT * CC;
      const size_t bT = (size_t)b * TT;
      const float* lgc = lg + c;

      float av = lg[c];                  // alpha, duplicated across halves

      // returns bpi (identical on both lane halves)
      auto vstep = [&](int t, float logit_c) -> int {
        float base = (lane < 32) ? av : xor16f(av, lane);
        float S[16];
        float x;
        S[0] = base + tr2[0];
        ROR(x, base, 1);  S[1]  = x + tr2[1];
        ROR(x, base, 2);  S[2]  = x + tr2[2];
        ROR(x, base, 3);  S[3]  = x + tr2[3];
        ROR(x, base, 4);  S[4]  = x + tr2[4];
        ROR(x, base, 5);  S[5]  = x + tr2[5];
        ROR(x, base, 6);  S[6]  = x + tr2[6];
        ROR(x, base, 7);  S[7]  = x + tr2[7];
        ROR(x, base, 8);  S[8]  = x + tr2[8];
        ROR(x, base, 9);  S[9]  = x + tr2[9];
        ROR(x, base, 10); S[10] = x + tr2[10];
        ROR(x, base, 11); S[11] = x + tr2[11];
        ROR(x, base, 12); S[12] = x + tr2[12];
        ROR(x, base, 13); S[13] = x + tr2[13];
        ROR(x, base, 14); S[14] = x + tr2[14];
        ROR(x, base, 15); S[15] = x + tr2[15];

        // max via triples (clang fuses to v_max3): exact, order-independent
        float a = fmaxf(fmaxf(S[0], S[1]), S[2]);
        float bq = fmaxf(fmaxf(S[3], S[4]), S[5]);
        float cq = fmaxf(fmaxf(S[6], S[7]), S[8]);
        float dq = fmaxf(fmaxf(S[9], S[10]), S[11]);
        float eq = fmaxf(fmaxf(S[12], S[13]), S[14]);
        float best = fmaxf(fmaxf(fmaxf(a, bq), fmaxf(cq, dq)),
                           fmaxf(eq, S[15]));

        // first-index = min prev-tag where equal (order-independent, exact)
        int t8[16];
#pragma unroll
        for (int kk = 0; kk < 16; ++kk)
          t8[kk] = (S[kk] == best) ? pidx[kk] : 63;
        int ma = min(min(t8[0], t8[1]), t8[2]);
        int mb = min(min(t8[3], t8[4]), t8[5]);
        int mc = min(min(t8[6], t8[7]), t8[8]);
        int md = min(min(t8[9], t8[10]), t8[11]);
        int me = min(min(t8[12], t8[13]), t8[14]);
        int bi = min(min(min(ma, mb), min(mc, md)), min(me, t8[15]));

        float ov = xor32f(best, lane);
        int   oi = xor32i(bi, lane);
        bool take = (ov > best) || (ov == best && oi < bi);
        best = take ? ov : best;
        int bpi = take ? oi : bi;
        av = logit_c + best;

        if (lane < 32) bp_s[(t - 1) * CC + c] = (unsigned char)bpi;
        return bpi;
      };

      // chunked 8-step double-bank logit pipeline + per-4-step map compose
      float Abk[8], Bbk[8];
      auto loadB = [&](float (&bk)[8], int t0) {
#pragma unroll
        for (int s = 0; s < 8; ++s) {
          int tt = t0 + s; tt = tt < len ? tt : len - 1;
          bk[s] = lgc[tt * CC];
        }
      };
      // chunks start at t0 ≡ 1 (mod 8) → group-ends (t≡0 mod 4) at s=3,7;
      // the 4-step history never crosses a chunk boundary.
      auto runB = [&](float (&bk)[8], int t0) {
        int h1 = 0, h2 = 0, h3 = 0;      // bpi at t-1, t-2, t-3
#pragma unroll
        for (int s = 0; s < 8; ++s) {
          int tt = t0 + s;
          if (tt < len) {
            int bpi = vstep(tt, bk[s]);
            if ((tt & 3) == 0) {
              // compose 4 maps: m1=bp[t], m2=bp[t-1]∘m1, m3=bp[t-2]∘m2,
              // m4=bp[t-3]∘m3.  Pure integer gathers of final bpi values.
              int m2 = __builtin_amdgcn_ds_bpermute(bpi << 2, h1);
              int m3 = __builtin_amdgcn_ds_bpermute(m2 << 2, h2);
              int m4 = __builtin_amdgcn_ds_bpermute(m3 << 2, h3);
              unsigned packed = (unsigned)bpi | ((unsigned)m2 << 8) |
                                ((unsigned)m3 << 16) | ((unsigned)m4 << 24);
              if (lane < 32) gp_s[((tt >> 2) - 1) * CC + c] = packed;
            }
            h3 = h2; h2 = h1; h1 = bpi;
          }
        }
      };
      loadB(Abk, 1);
      for (int t0 = 1; t0 < len; t0 += 16) {
        loadB(Bbk, t0 + 8);
        runB(Abk, t0);
        if (t0 + 8 < len) {
          loadB(Abk, t0 + 16);
          runB(Bbk, t0 + 8);
        }
      }

      // last tag: argmax over c (first index on ties)
      float v = av; int idx = c;
#pragma unroll
      for (int d = 1; d < 32; d <<= 1) {
        float v2 = __shfl_xor(v, d, 32);
        int   i2 = __shfl_xor(idx, d, 32);
        if (v2 > v || (v2 == v && i2 < idx)) { v = v2; idx = i2; }
      }

      // backtrace: ragged head via byte rows, then 4-step jumps via gp rows
      if (lane == 0) {
        int tag = idx;
        int t = len - 1;
        tag_s[t] = (unsigned char)tag;
        while (t > 0 && (t & 3) != 0) {
          tag = bp_s[(t - 1) * CC + tag];
          --t;
          tag_s[t] = (unsigned char)tag;
        }
        while (t >= 4) {
          unsigned u = gp_s[((t >> 2) - 1) * CC + tag];
          tag_s[t - 1] = (unsigned char)(u & 255);
          tag_s[t - 2] = (unsigned char)((u >> 8) & 255);
          tag_s[t - 3] = (unsigned char)((u >> 16) & 255);
          tag = (int)(u >> 24);
          tag_s[t - 4] = (unsigned char)tag;
          t -= 4;
        }
      }

      // coalesced tag store (+ zero padding)
#pragma unroll
      for (int j = 0; j < 8; ++j) {
        int tt = lane + 64 * j;
        float val = (tt < len) ? (float)tag_s[tt] : 0.0f;
        out[bT + tt] = val;
      }
    }

  } else {
    // ================= Forward wave (scaled linear domain) =================
    float E[16];
#pragma unroll
    for (int kk = 0; kk < 16; ++kk) {
      int p = pr * 16 + ((i - kk) & 15);
      E[kk] = EXP2F(trans[p * CC + c] * LOG2E);
    }

    float loss_acc = 0.0f;

    for (int sq = 0; sq < 2; ++sq) {
      const int b = sq ? bs1 : bs0;
      if (b < 0) break;
      const int len = seqlen[b];
      const float* lg = logits + (size_t)b * TT * CC;
      const int* lab = labels + (size_t)b * TT;
      const float* lgc = lg + c;

      float P   = EXP2F(lg[c] * LOG2E);  // scaled linear alpha for column c
      float Acc = 0.0f;                  // accumulated log2 scale (uniform)

      auto fstep = [&](float raw_logit) {
        float el = EXP2F(raw_logit * LOG2E);   // off the serial P-chain
        float base = (lane < 32) ? P : xor16f(P, lane);
        float x;
        float a0 = base * E[0];
        ROR(x, base, 1);  float a1 = x * E[1];
        ROR(x, base, 2);  float a2 = x * E[2];
        ROR(x, base, 3);  float a3 = x * E[3];
        ROR(x, base, 4);  a0 = fmaf(x, E[4],  a0);
        ROR(x, base, 5);  a1 = fmaf(x, E[5],  a1);
        ROR(x, base, 6);  a2 = fmaf(x, E[6],  a2);
        ROR(x, base, 7);  a3 = fmaf(x, E[7],  a3);
        ROR(x, base, 8);  a0 = fmaf(x, E[8],  a0);
        ROR(x, base, 9);  a1 = fmaf(x, E[9],  a1);
        ROR(x, base, 10); a2 = fmaf(x, E[10], a2);
        ROR(x, base, 11); a3 = fmaf(x, E[11], a3);
        ROR(x, base, 12); a0 = fmaf(x, E[12], a0);
        ROR(x, base, 13); a1 = fmaf(x, E[13], a1);
        ROR(x, base, 14); a2 = fmaf(x, E[14], a2);
        ROR(x, base, 15); a3 = fmaf(x, E[15], a3);
        float part = (a0 + a1) + (a2 + a3);      // this lane's 16-row partial
        float oth  = xor32f(part, lane);         // other row's partial
        P = el * (part + oth);
      };

      auto renorm = [&]() {
        float m = P, y;
        ROR(y, m, 8); m = fmaxf(m, y);
        ROR(y, m, 4); m = fmaxf(m, y);
        ROR(y, m, 2); m = fmaxf(m, y);
        ROR(y, m, 1); m = fmaxf(m, y);
        m = fmaxf(m, xor16f(m, lane));
        int e = (int)(__float_as_uint(m) >> 23) - 127;  // floor(log2 m)
        P = ldexpf(P, -e);                              // exact scaling
        Acc += (float)e;
      };

      float Abk[8], Bbk[8];
      auto loadB = [&](float (&bk)[8], int t0) {
#pragma unroll
        for (int s = 0; s < 8; ++s) {
          int tt = t0 + s; tt = tt < len ? tt : len - 1;
          bk[s] = lgc[tt * CC];
        }
      };
      auto runB = [&](float (&bk)[8], int t0) {
#pragma unroll
        for (int s = 0; s < 8; ++s) {
          int tt = t0 + s;
          if (tt < len) {
            fstep(bk[s]);
            if ((tt & 3) == 0) renorm();
          }
        }
      };
      loadB(Abk, 1);
      for (int t0 = 1; t0 < len; t0 += 16) {
        loadB(Bbk, t0 + 8);
        runB(Abk, t0);
        if (t0 + 8 < len) {
          loadB(Abk, t0 + 16);
          runB(Bbk, t0 + 8);
        }
      }

      // gold-path score (unary + binary), lane-parallel over t
      float uacc = 0.0f, bacc = 0.0f;
#pragma unroll
      for (int j = 0; j < 8; ++j) {
        int tt = lane + 64 * j;
        if (tt < len) {
          int lt = lab[tt];
          uacc += lg[tt * CC + lt];
          if (tt + 1 < len) {
            int ln = lab[tt + 1];
            bacc += trans[lt * CC + ln];
          }
        }
      }
#pragma unroll
      for (int d = 32; d >= 1; d >>= 1) {
        uacc += __shfl_xor(uacc, d);
        bacc += __shfl_xor(bacc, d);
      }

      // log partition: rotate-fold sum of the 32 scaled alphas + scale
      float ss = P, y2;
      ROR(y2, ss, 8); ss += y2;
      ROR(y2, ss, 4); ss += y2;
      ROR(y2, ss, 2); ss += y2;
      ROR(y2, ss, 1); ss += y2;
      ss += xor16f(ss, lane);
      float log_norm = LN2 * (Acc + LOG2F(ss));

      loss_acc += (uacc + bacc - log_norm);
    }

    if (lane == 0) {
      atomicAdd(out + (size_t)BB * TT, loss_acc * (-1.0f / BB));
    }
  }
}

extern "C" void kernel_launch(void* const* d_in, const int* in_sizes, int n_in,
                              void* d_out, int out_size, void* d_ws, size_t ws_size,
                              hipStream_t stream) {
  const float* logits = (const float*)d_in[0];
  const int*   seqlen = (const int*)d_in[1];
  const int*   labels = (const int*)d_in[2];
  const float* trans  = (const float*)d_in[3];
  float* out = (float*)d_out;

  if (d_ws != nullptr && ws_size >= BB * sizeof(int)) {
    int* perm = (int*)d_ws;
    schedule_kernel<<<1, TT, 0, stream>>>(seqlen, perm, out);
    crf_kernel<<<dim3(BB / 2), dim3(128), 0, stream>>>(
        logits, seqlen, labels, trans, out, perm);
  } else {
    zero_loss_kernel<<<1, 64, 0, stream>>>(out);
    crf_kernel<<<dim3(BB), dim3(128), 0, stream>>>(
        logits, seqlen, labels, trans, out, nullptr);
  }
}